// Round 12
// baseline (149.291 us; speedup 1.0000x reference)
//
#include <hip/hip_runtime.h>
#include <hip/hip_bf16.h>
#include <math.h>

#define SELU_SCALE 1.0507009873554805f
#define SELU_ALPHA 1.6732632423543772f

static constexpr int B_ = 16, T_ = 16, L_ = 512, H_ = 768;
static constexpr int WSZ = 768 * 768;          // one weight matrix, elements
static constexpr int HNELEM = B_ * L_ * H_;    // 6291456
static constexpr int DJELEM = B_ * T_ * H_;    // 196608
// combined bf16 staging buffer layout: [hn | W1 | W2 | dj-gather]
static constexpr int ALLELEM = HNELEM + 2 * WSZ + DJELEM;   // 7667712 (/2048 = 3744)

typedef __bf16 bf16x8 __attribute__((ext_vector_type(8)));
typedef float  f32x4  __attribute__((ext_vector_type(4)));

__device__ __forceinline__ float bf_lo(unsigned u) { return __uint_as_float(u << 16); }
__device__ __forceinline__ float bf_hi(unsigned u) { return __uint_as_float(u & 0xFFFF0000u); }

__device__ __forceinline__ float selu_core(float x) {
    float e = fmaf(__expf(x), SELU_ALPHA, -SELU_ALPHA);
    return x > 0.0f ? x : e;
}

// LDS k-segment slot swizzle: slot = seg ^ ((row>>1)&3). Measured 0 conflicts
// for these write/read patterns. Note xsw(r+16) == xsw(r), so fragment offsets
// are affine in the 16-row fragment index.
__device__ __forceinline__ int xsw(int r) { return (r >> 1) & 3; }

__device__ __forceinline__ bf16x8 pack8(float4 a, float4 b) {
    bf16x8 o;
    o[0] = (__bf16)a.x; o[1] = (__bf16)a.y; o[2] = (__bf16)a.z; o[3] = (__bf16)a.w;
    o[4] = (__bf16)b.x; o[5] = (__bf16)b.y; o[6] = (__bf16)b.z; o[7] = (__bf16)b.w;
    return o;
}

// ---------------- prep: {hn, W1, W2, dec-gather} -> bf16 (one pass, ~7us) -------
// r3/r4-proven bit-identical (same RTN rounding as the old in-register staging).
// Enables gemm_k's global_load_lds DMA staging. Also zeroes the loss accumulator.
__global__ __launch_bounds__(256) void prep_k(
        const float* __restrict__ hn, const float* __restrict__ dec,
        const float* __restrict__ w1, const float* __restrict__ w2,
        const int* __restrict__ Yi,
        __bf16* __restrict__ allb, float* __restrict__ out) {
    if (blockIdx.x == 0 && threadIdx.x == 0) out[0] = 0.0f;
    int idx = (blockIdx.x * 256 + threadIdx.x) * 8;
    const float* src;
    if (idx < HNELEM) {
        src = hn + idx;
    } else if (idx < HNELEM + WSZ) {
        src = w1 + (idx - HNELEM);
    } else if (idx < HNELEM + 2 * WSZ) {
        src = w2 + (idx - HNELEM - WSZ);
    } else {
        int e = idx - (HNELEM + 2 * WSZ);      // < 196608
        int r = e / 768, c = e - r * 768;      // r = bt, 8 elems stay in-row
        src = dec + ((size_t)((r >> 4) * L_ + Yi[r])) * H_ + c;
    }
    float4 a = *(const float4*)src;
    float4 b = *(const float4*)(src + 4);
    *(bf16x8*)(allb + idx) = pack8(a, b);
}

// ---------------- fused NT GEMM: gload_lds + counted-vmcnt, 128x64 / 3 blk/CU ---
// r11 post-mortem: 396-block grid was imbalanced (140 CUs x2 blocks, 116 x1) at
// ~8 waves/CU. Same r10-proven DMA pipeline, tile narrowed to 128m x 64n:
// 64x12 WE + 24 WD = 792 blocks ~= 3.1/CU (12 waves/CU, near-even makespan).
// Stage = 3 gload_lds/thread (A 2 + B 1) -> steady wait vmcnt(3) (two stages in
// flight = 6 ops, retire the oldest 3; in-order vm retirement). 3 LDS buffers x
// 12KB = 36KB -> 3 blocks/CU. lb(256,3): acc 4x2 = 32 VGPR, fits the 85 cap.
// Tail audit: ITER(21) waits {21,22}->retire 21, stages 23; ITER(22) waits
// {22,23}->retire 22, stages nothing; final tile 23 drains vmcnt(0)+barrier
// (the r9 race fix pattern). STAGE(t+2) issues AFTER barrier(t); buf[(t+2)%3]
// was last read at iter t-1, sealed by that barrier. sched_barrier(0) pins
// COMPUTE's ds_reads below the sync. Pre-swizzled DMA source (xsw; LDS linear
// per m104/m173), measured-0-conflict fragment reads.
__global__ __launch_bounds__(256, 3) void gemm_k(
        const __bf16* __restrict__ allb,
        __bf16* __restrict__ web, float* __restrict__ wdf) {
    __shared__ __bf16 sm[3][6144];   // [buf][A(4096) | B(2048)] = 36 KB

    int bx = blockIdx.x;
    const __bf16 *Ab, *Bb; int m0, n0; bool wd;
    if (bx < 768) {                      // WE: 64 m-tiles(128) x 12 n-tiles(64)
        wd = false; Ab = allb; Bb = allb + HNELEM;
        m0 = (bx & 63) * 128; n0 = (bx >> 6) * 64;
    } else {                             // WD: 2 m-tiles x 12 n-tiles
        wd = true; bx -= 768;
        Ab = allb + HNELEM + 2 * WSZ; Bb = allb + HNELEM + WSZ;
        m0 = (bx & 1) * 128;  n0 = (bx >> 1) * 64;
    }

    const int tid = threadIdx.x, wave = tid >> 6, lane = tid & 63;
    const int wm = (wave >> 1) * 64, wn = (wave & 1) * 32;
    const int lr = lane & 15, q = lane >> 4;
    const int l4 = lane >> 2, sl = lane & 3;

    // staging rows: A instr0 -> rows wave*16+l4 (0..63), A instr1 -> +64,
    // B instr -> B rows wave*16+l4 (0..63). lane's 16B lands at
    // ldsBase(wave) + lane*16 (linear); global seg pre-swizzled with xsw.
    const int ar0 = wave * 16 + l4, ar1 = ar0 + 64;
    const __bf16* gA0 = Ab + (size_t)(m0 + ar0) * 768 + (sl ^ xsw(ar0)) * 8;
    const __bf16* gA1 = Ab + (size_t)(m0 + ar1) * 768 + (sl ^ xsw(ar1)) * 8;
    const __bf16* gB0 = Bb + (size_t)(n0 + ar0) * 768 + (sl ^ xsw(ar0)) * 8;
    const int ldA0 = wave * 512;            // A rows 0..63 slice (elements)
    const int ldA1 = 2048 + wave * 512;     // A rows 64..127
    const int ldB0 = 4096 + wave * 512;     // B rows 0..63

    // fragment base offsets (xsw(r+16)==xsw(r) -> affine in fragment index)
    const int aoff0 = (wm + lr) * 32 + (q ^ xsw(wm + lr)) * 8;
    const int boff0 = 4096 + (wn + lr) * 32 + (q ^ xsw(wn + lr)) * 8;

    f32x4 acc[4][2] = {};

#define STAGE(b, kk)                                                                        \
    {                                                                                       \
        __builtin_amdgcn_global_load_lds((const __attribute__((address_space(1))) void*)(gA0 + (kk)), \
            (__attribute__((address_space(3))) void*)&sm[b][ldA0], 16, 0, 0);               \
        __builtin_amdgcn_global_load_lds((const __attribute__((address_space(1))) void*)(gA1 + (kk)), \
            (__attribute__((address_space(3))) void*)&sm[b][ldA1], 16, 0, 0);               \
        __builtin_amdgcn_global_load_lds((const __attribute__((address_space(1))) void*)(gB0 + (kk)), \
            (__attribute__((address_space(3))) void*)&sm[b][ldB0], 16, 0, 0);               \
    }

#define COMPUTE(b)                                                                          \
    {                                                                                       \
        bf16x8 af[4], bfr[2];                                                               \
        _Pragma("unroll")                                                                   \
        for (int i = 0; i < 4; ++i) af[i]  = *(const bf16x8*)&sm[b][aoff0 + i * 512];       \
        _Pragma("unroll")                                                                   \
        for (int j = 0; j < 2; ++j) bfr[j] = *(const bf16x8*)&sm[b][boff0 + j * 512];       \
        _Pragma("unroll")                                                                   \
        for (int i = 0; i < 4; ++i)                                                         \
            _Pragma("unroll")                                                               \
            for (int j = 0; j < 2; ++j)                                                     \
                acc[i][j] = __builtin_amdgcn_mfma_f32_16x16x32_bf16(af[i], bfr[j], acc[i][j], 0, 0, 0); \
    }

// one steady-state k-step: wait until the oldest in-flight stage landed
// (<=3 outstanding after wait, in-order retirement), barrier, prefetch tile
// tt+2, compute tile tt. Valid for tt <= 22 (two stages in flight at the wait).
#define ITER(tt, bc, bs)                                                                    \
    {                                                                                       \
        asm volatile("s_waitcnt vmcnt(3)" ::: "memory");                                    \
        __builtin_amdgcn_s_barrier();                                                       \
        __builtin_amdgcn_sched_barrier(0);                                                  \
        if ((tt) + 2 < 24) STAGE(bs, ((tt) + 2) * 32)                                       \
        COMPUTE(bc)                                                                         \
    }

    // prologue: stage tiles 0 and 1 (no drain -- ITER's vmcnt(3) covers it)
    STAGE(0, 0)
    STAGE(1, 32)

#pragma unroll 1
    for (int g = 0; g < 7; ++g) {       // tiles 0..20
        const int t0g = g * 3;
        ITER(t0g + 0, 0, 2)
        ITER(t0g + 1, 1, 0)
        ITER(t0g + 2, 2, 1)
    }
    ITER(21, 0, 2)                      // stages tile 23 into buf 2
    ITER(22, 1, 0)                      // stages nothing (22 retired by this wait)
    // FINAL tile 23: only 3 ops outstanding here -- vmcnt(3) would NOT wait.
    // Drain fully, then one barrier so all waves' DMA is visible.
    asm volatile("s_waitcnt vmcnt(0)" ::: "memory");
    __builtin_amdgcn_s_barrier();
    __builtin_amdgcn_sched_barrier(0);
    COMPUTE(2)
#undef ITER
#undef STAGE
#undef COMPUTE

#pragma unroll
    for (int i = 0; i < 4; ++i)
#pragma unroll
        for (int j = 0; j < 2; ++j)
#pragma unroll
            for (int r = 0; r < 4; ++r) {
                int row = m0 + wm + i * 16 + q * 4 + r;
                int col = n0 + wn + j * 16 + lr;
                if (!wd) web[(size_t)row * 768 + col] = (__bf16)acc[i][j][r];
                else     wdf[(size_t)row * 768 + col] = acc[i][j][r];
            }
}

// ---------------- scores: LDS-free, register-cached, z-split 4 for occupancy ----
// Block = (b, 16 l rows, 4 t's). 256 thr = 16 ls x 16 hc. Thread owns the 48
// h-elements {hc*8 + j*128 + e}, keeps we (unpacked bf16) and V in registers,
// streams wd[t] (f32, L2-resident) per t. Grid 16x32x4 = 2048 blocks = 8/CU =
// 32 waves/CU (r11-verified win). Xindex monotone in t -> valid t's form a
// PREFIX per wave: tend computed once, loop branch-free, fully-masked waves
// exit BEFORE the 24 we/vv loads. unroll 2 interleaves two t-chains. lb(256,4)
// keeps we/vv hoisted (r2: no-hint sank them into the loop).
__global__ __launch_bounds__(256, 4) void scores_k(
        const __bf16* __restrict__ web, const float* __restrict__ wdf,
        const float* __restrict__ V, const int* __restrict__ Xi,
        float* __restrict__ scores) {
    const int b  = blockIdx.x;
    const int l0 = ((int)gridDim.y - 1 - (int)blockIdx.y) * 16;   // heavy first
    const int t0 = blockIdx.z * 4;
    const int tid = threadIdx.x;
    const int ls = tid >> 4, hc = tid & 15;
    const int l  = l0 + ls;
    const int h0 = hc * 8;
    const int bT = b * T_;

    const int wmaxl = l0 + ((tid >> 6) << 2) + 3;   // wave covers ls = 4w..4w+3
    if (wmaxl < Xi[bT + t0]) return;                // whole window masked (prefix)
    int tend = t0;
#pragma unroll
    for (int tt = t0; tt < t0 + 4; ++tt)
        if (wmaxl >= Xi[bT + tt]) tend = tt + 1;    // valid t's are a prefix

    float we[48], vv[48];
    const __bf16* wr = web + ((size_t)(b * L_ + l)) * H_ + h0;
#pragma unroll
    for (int j = 0; j < 6; ++j) {
        uint4 u = *(const uint4*)(wr + j * 128);
        we[j*8+0] = bf_lo(u.x); we[j*8+1] = bf_hi(u.x);
        we[j*8+2] = bf_lo(u.y); we[j*8+3] = bf_hi(u.y);
        we[j*8+4] = bf_lo(u.z); we[j*8+5] = bf_hi(u.z);
        we[j*8+6] = bf_lo(u.w); we[j*8+7] = bf_hi(u.w);
    }
    const float* vp = V + h0;
#pragma unroll
    for (int j = 0; j < 6; ++j) {
        float4 a = *(const float4*)(vp + j * 128);
        float4 c = *(const float4*)(vp + j * 128 + 4);
        vv[j*8+0] = a.x; vv[j*8+1] = a.y; vv[j*8+2] = a.z; vv[j*8+3] = a.w;
        vv[j*8+4] = c.x; vv[j*8+5] = c.y; vv[j*8+6] = c.z; vv[j*8+7] = c.w;
    }

#pragma unroll 2
    for (int t = t0; t < tend; ++t) {
        const float* wdp = wdf + ((size_t)(bT + t)) * H_ + h0;
        float a0 = 0.f, a1 = 0.f, a2 = 0.f, a3 = 0.f;
#pragma unroll
        for (int j = 0; j < 6; ++j) {
            float4 x = *(const float4*)(wdp + j * 128);
            float4 y = *(const float4*)(wdp + j * 128 + 4);
            a0 = fmaf(selu_core(we[j*8+0] + x.x), vv[j*8+0], a0);
            a1 = fmaf(selu_core(we[j*8+1] + x.y), vv[j*8+1], a1);
            a2 = fmaf(selu_core(we[j*8+2] + x.z), vv[j*8+2], a2);
            a3 = fmaf(selu_core(we[j*8+3] + x.w), vv[j*8+3], a3);
            a0 = fmaf(selu_core(we[j*8+4] + y.x), vv[j*8+4], a0);
            a1 = fmaf(selu_core(we[j*8+5] + y.y), vv[j*8+5], a1);
            a2 = fmaf(selu_core(we[j*8+6] + y.z), vv[j*8+6], a2);
            a3 = fmaf(selu_core(we[j*8+7] + y.w), vv[j*8+7], a3);
        }
        float dot = (a0 + a1) + (a2 + a3);
        dot += __shfl_xor(dot, 1);
        dot += __shfl_xor(dot, 2);
        dot += __shfl_xor(dot, 4);
        dot += __shfl_xor(dot, 8);
        if (hc == 0) {
            dot *= SELU_SCALE;
            float sc = dot > 0.0f ? SELU_SCALE * dot
                                  : SELU_SCALE * SELU_ALPHA * (__expf(dot) - 1.0f);
            scores[((size_t)(bT + t)) * L_ + l] = sc;
        }
    }
}

// ---------------- per-(b,t) masked logsumexp + gold + mean (atomic) -------------
__global__ __launch_bounds__(64) void loss_k(
        const float* __restrict__ scores, const int* __restrict__ Xi,
        const int* __restrict__ Yi, float* __restrict__ out) {
    const int bt = blockIdx.x;
    const int lane = threadIdx.x;
    const int X = Xi[bt];
    const int Y = Yi[bt];
    const float* row = scores + (size_t)bt * L_;

    float m = -INFINITY;
    for (int l = X + lane; l < L_; l += 64) m = fmaxf(m, row[l]);
#pragma unroll
    for (int off = 32; off > 0; off >>= 1) m = fmaxf(m, __shfl_xor(m, off));

    float s = 0.0f;
    for (int l = X + lane; l < L_; l += 64) s += __expf(row[l] - m);
#pragma unroll
    for (int off = 32; off > 0; off >>= 1) s += __shfl_xor(s, off);

    if (lane == 0)
        atomicAdd(out, (m + __logf(s) - row[Y]) * (1.0f / (B_ * T_)));
}

// ---------------- launch ----------------
extern "C" void kernel_launch(void* const* d_in, const int* in_sizes, int n_in,
                              void* d_out, int out_size, void* d_ws, size_t ws_size,
                              hipStream_t stream) {
    const float* hn  = (const float*)d_in[0];
    const float* dec = (const float*)d_in[1];
    const float* W1  = (const float*)d_in[2];
    const float* W2  = (const float*)d_in[3];
    const float* V   = (const float*)d_in[4];
    const int*   Xi  = (const int*)d_in[5];
    const int*   Yi  = (const int*)d_in[6];
    float* out = (float*)d_out;

    char* ws = (char*)d_ws;
    size_t off = 0;
    auto alloc = [&](size_t bytes) -> char* {
        char* p = ws + off;
        off += (bytes + 255) & ~(size_t)255;
        return p;
    };
    __bf16* web    = (__bf16*)alloc((size_t)B_ * L_ * H_ * 2);
    float*  wdf    = (float*)alloc((size_t)B_ * T_ * H_ * 4);
    float*  scores = (float*)alloc((size_t)B_ * T_ * L_ * 4);
    __bf16* allb   = (__bf16*)alloc((size_t)ALLELEM * 2);

    prep_k<<<ALLELEM / (256 * 8), 256, 0, stream>>>(hn, dec, W1, W2, Yi, allb, out);
    gemm_k<<<768 + 24, 256, 0, stream>>>(allb, web, wdf);
    scores_k<<<dim3(B_, L_ / 16, 4), 256, 0, stream>>>(web, wdf, V, Xi, scores);
    loss_k<<<B_ * T_, 64, 0, stream>>>(scores, Xi, Yi, out);
}

// Round 13
// 144.405 us; speedup vs baseline: 1.0338x; 1.0338x over previous
//
#include <hip/hip_runtime.h>
#include <hip/hip_bf16.h>
#include <math.h>

#define SELU_SCALE 1.0507009873554805f
#define SELU_ALPHA 1.6732632423543772f

static constexpr int B_ = 16, T_ = 16, L_ = 512, H_ = 768;
static constexpr int WSZ = 768 * 768;          // one weight matrix, elements
static constexpr int HNELEM = B_ * L_ * H_;    // 6291456
static constexpr int DJELEM = B_ * T_ * H_;    // 196608
// combined bf16 staging buffer layout: [hn | W1 | W2 | dj-gather]
static constexpr int ALLELEM = HNELEM + 2 * WSZ + DJELEM;   // 7667712 (/2048 = 3744)

typedef __bf16 bf16x8 __attribute__((ext_vector_type(8)));
typedef float  f32x4  __attribute__((ext_vector_type(4)));

__device__ __forceinline__ float bf_lo(unsigned u) { return __uint_as_float(u << 16); }
__device__ __forceinline__ float bf_hi(unsigned u) { return __uint_as_float(u & 0xFFFF0000u); }

__device__ __forceinline__ float selu_core(float x) {
    float e = fmaf(__expf(x), SELU_ALPHA, -SELU_ALPHA);
    return x > 0.0f ? x : e;
}

// LDS k-segment slot swizzle: slot = seg ^ ((row>>1)&3). Measured 0 conflicts
// for these write/read patterns. Note xsw(r+16) == xsw(r), so fragment offsets
// are affine in the 16-row fragment index.
__device__ __forceinline__ int xsw(int r) { return (r >> 1) & 3; }

__device__ __forceinline__ bf16x8 pack8(float4 a, float4 b) {
    bf16x8 o;
    o[0] = (__bf16)a.x; o[1] = (__bf16)a.y; o[2] = (__bf16)a.z; o[3] = (__bf16)a.w;
    o[4] = (__bf16)b.x; o[5] = (__bf16)b.y; o[6] = (__bf16)b.z; o[7] = (__bf16)b.w;
    return o;
}

// ---------------- prep: {hn, W1, W2, dec-gather} -> bf16 (one pass, ~7us) -------
// r3/r4-proven bit-identical (same RTN rounding as the old in-register staging).
// Enables gemm_k's global_load_lds DMA staging. Also zeroes the loss accumulator.
__global__ __launch_bounds__(256) void prep_k(
        const float* __restrict__ hn, const float* __restrict__ dec,
        const float* __restrict__ w1, const float* __restrict__ w2,
        const int* __restrict__ Yi,
        __bf16* __restrict__ allb, float* __restrict__ out) {
    if (blockIdx.x == 0 && threadIdx.x == 0) out[0] = 0.0f;
    int idx = (blockIdx.x * 256 + threadIdx.x) * 8;
    const float* src;
    if (idx < HNELEM) {
        src = hn + idx;
    } else if (idx < HNELEM + WSZ) {
        src = w1 + (idx - HNELEM);
    } else if (idx < HNELEM + 2 * WSZ) {
        src = w2 + (idx - HNELEM - WSZ);
    } else {
        int e = idx - (HNELEM + 2 * WSZ);      // < 196608
        int r = e / 768, c = e - r * 768;      // r = bt, 8 elems stay in-row
        src = dec + ((size_t)((r >> 4) * L_ + Yi[r])) * H_ + c;
    }
    float4 a = *(const float4*)src;
    float4 b = *(const float4*)(src + 4);
    *(bf16x8*)(allb + idx) = pack8(a, b);
}

// ---------------- fused NT GEMM: gload_lds + counted-vmcnt, depth-4 pipeline ----
// r12 post-mortem: 128x64 tile REGRESSED (+7us) -- staging bytes/output rose
// 24->36B (B-panel reuse halved); with the DMA pipeline working, staging
// efficiency beats occupancy. REVERTED to r11's 128x128 / 396-block geometry.
// Single change: pipeline depth 3->4 (64KB LDS, 2 blk/CU at lb(256,2)). Steady
// wait vmcnt(8): TWO full stages (8 ops) stay in flight across each barrier --
// 2 tile-times of latency slack instead of 1. Tail audit (depth-4): ITER(21)
// waits with {21,22,23}=12 in flight -> retires 21; t=22 peeled with vmcnt(4)
// ({22,23}=8); t=23 with vmcnt(0). Write-after-read: STAGE(t+3) targets
// buf (t-1)%4, last read at iter t-1, sealed by ITER(t)'s barrier. Cross-wave
// visibility: every wave drains its OWN tile-t ops before the shared barrier.
// sched_barrier(0) pins COMPUTE's ds_reads below the sync. Pre-swizzled DMA
// source (xsw; LDS linear per m104/m173), measured-0-conflict fragment reads.
__global__ __launch_bounds__(256, 2) void gemm_k(
        const __bf16* __restrict__ allb,
        __bf16* __restrict__ web, float* __restrict__ wdf) {
    __shared__ __bf16 sm[4][2][4096];   // [buf][A/B][128*32] = 64 KB

    int bx = blockIdx.x;
    const __bf16 *Ab, *Bb; int m0, n0; bool wd;
    if (bx < 384) {                      // WE: 64 m-tiles x 6 n-chunks
        wd = false; Ab = allb; Bb = allb + HNELEM;
        m0 = (bx & 63) * 128; n0 = (bx >> 6) * 128;
    } else {                             // WD: 2 m-tiles x 6 n-chunks
        wd = true; bx -= 384;
        Ab = allb + HNELEM + 2 * WSZ; Bb = allb + HNELEM + WSZ;
        m0 = (bx & 1) * 128;  n0 = (bx >> 1) * 128;
    }

    const int tid = threadIdx.x, wave = tid >> 6, lane = tid & 63;
    const int wm = (wave >> 1) * 64, wn = (wave & 1) * 64;
    const int lr = lane & 15, q = lane >> 4;
    const int l4 = lane >> 2, sl = lane & 3;

    // staging rows: instr0 -> rows wave*16 + l4 (0..63), instr1 -> +64.
    // lane's 16B lands at ldsBase + lane*16 (linear); pre-swizzled global seg.
    const int ar0 = wave * 16 + l4, ar1 = ar0 + 64;
    const __bf16* gA0 = Ab + (size_t)(m0 + ar0) * 768 + (sl ^ xsw(ar0)) * 8;
    const __bf16* gA1 = Ab + (size_t)(m0 + ar1) * 768 + (sl ^ xsw(ar1)) * 8;
    const __bf16* gB0 = Bb + (size_t)(n0 + ar0) * 768 + (sl ^ xsw(ar0)) * 8;
    const __bf16* gB1 = Bb + (size_t)(n0 + ar1) * 768 + (sl ^ xsw(ar1)) * 8;
    const int ld0 = wave * 512;          // element offset of this wave's 1KB slice
    const int ld1 = 2048 + wave * 512;

    // fragment base offsets (xsw(r+16)==xsw(r) -> affine in fragment index)
    const int aoff0 = (wm + lr) * 32 + (q ^ xsw(wm + lr)) * 8;
    const int boff0 = (wn + lr) * 32 + (q ^ xsw(wn + lr)) * 8;

    f32x4 acc[4][4] = {};

#define STAGE(b, kk)                                                                        \
    {                                                                                       \
        __builtin_amdgcn_global_load_lds((const __attribute__((address_space(1))) void*)(gA0 + (kk)), \
            (__attribute__((address_space(3))) void*)&sm[b][0][ld0], 16, 0, 0);             \
        __builtin_amdgcn_global_load_lds((const __attribute__((address_space(1))) void*)(gA1 + (kk)), \
            (__attribute__((address_space(3))) void*)&sm[b][0][ld1], 16, 0, 0);             \
        __builtin_amdgcn_global_load_lds((const __attribute__((address_space(1))) void*)(gB0 + (kk)), \
            (__attribute__((address_space(3))) void*)&sm[b][1][ld0], 16, 0, 0);             \
        __builtin_amdgcn_global_load_lds((const __attribute__((address_space(1))) void*)(gB1 + (kk)), \
            (__attribute__((address_space(3))) void*)&sm[b][1][ld1], 16, 0, 0);             \
    }

#define COMPUTE(b)                                                                          \
    {                                                                                       \
        bf16x8 af[4], bfr[4];                                                               \
        _Pragma("unroll")                                                                   \
        for (int i = 0; i < 4; ++i) af[i]  = *(const bf16x8*)&sm[b][0][aoff0 + i * 512];    \
        _Pragma("unroll")                                                                   \
        for (int j = 0; j < 4; ++j) bfr[j] = *(const bf16x8*)&sm[b][1][boff0 + j * 512];    \
        _Pragma("unroll")                                                                   \
        for (int i = 0; i < 4; ++i)                                                         \
            _Pragma("unroll")                                                               \
            for (int j = 0; j < 4; ++j)                                                     \
                acc[i][j] = __builtin_amdgcn_mfma_f32_16x16x32_bf16(af[i], bfr[j], acc[i][j], 0, 0, 0); \
    }

// one steady-state k-step (valid tt <= 21): three stages in flight (12 ops) at
// the wait; vmcnt(8) retires the oldest stage = tile tt (in-order retirement).
// Then barrier (all waves' tile-tt data visible), prefetch tt+3, compute tt.
#define ITER(tt, bc, bs)                                                                    \
    {                                                                                       \
        asm volatile("s_waitcnt vmcnt(8)" ::: "memory");                                    \
        __builtin_amdgcn_s_barrier();                                                       \
        __builtin_amdgcn_sched_barrier(0);                                                  \
        if ((tt) + 3 < 24) STAGE(bs, ((tt) + 3) * 32)                                       \
        COMPUTE(bc)                                                                         \
    }

    // prologue: stage tiles 0,1,2 (no drain -- ITER's vmcnt(8) covers it)
    STAGE(0, 0)
    STAGE(1, 32)
    STAGE(2, 64)

#pragma unroll 1
    for (int g = 0; g < 5; ++g) {       // tiles 0..19
        const int t0g = g * 4;
        ITER(t0g + 0, 0, 3)
        ITER(t0g + 1, 1, 0)
        ITER(t0g + 2, 2, 1)
        ITER(t0g + 3, 3, 2)
    }
    ITER(20, 0, 3)                      // stages tile 23 into buf 3
    ITER(21, 1, 0)                      // {21,22,23}=12 in flight: retires 21; stages nothing
    // t=22: {22,23}=8 in flight -- vmcnt(8) would NOT wait; vmcnt(4) retires 22.
    asm volatile("s_waitcnt vmcnt(4)" ::: "memory");
    __builtin_amdgcn_s_barrier();
    __builtin_amdgcn_sched_barrier(0);
    COMPUTE(2)
    // t=23: drain fully.
    asm volatile("s_waitcnt vmcnt(0)" ::: "memory");
    __builtin_amdgcn_s_barrier();
    __builtin_amdgcn_sched_barrier(0);
    COMPUTE(3)
#undef ITER
#undef STAGE
#undef COMPUTE

#pragma unroll
    for (int i = 0; i < 4; ++i)
#pragma unroll
        for (int j = 0; j < 4; ++j)
#pragma unroll
            for (int r = 0; r < 4; ++r) {
                int row = m0 + wm + i * 16 + q * 4 + r;
                int col = n0 + wn + j * 16 + lr;
                if (!wd) web[(size_t)row * 768 + col] = (__bf16)acc[i][j][r];
                else     wdf[(size_t)row * 768 + col] = acc[i][j][r];
            }
}

// ---------------- scores: LDS-free, register-cached, z-split 4 for occupancy ----
// Block = (b, 16 l rows, 4 t's). 256 thr = 16 ls x 16 hc. Thread owns the 48
// h-elements {hc*8 + j*128 + e}, keeps we (unpacked bf16) and V in registers,
// streams wd[t] (f32, L2-resident) per t. Grid 16x32x4 = 2048 blocks = 8/CU =
// 32 waves/CU (r11-verified win). Xindex monotone in t -> valid t's form a
// PREFIX per wave: tend computed once, loop branch-free, fully-masked waves
// exit BEFORE the 24 we/vv loads. unroll 2 interleaves two t-chains. lb(256,4)
// keeps we/vv hoisted (r2: no-hint sank them into the loop).
__global__ __launch_bounds__(256, 4) void scores_k(
        const __bf16* __restrict__ web, const float* __restrict__ wdf,
        const float* __restrict__ V, const int* __restrict__ Xi,
        float* __restrict__ scores) {
    const int b  = blockIdx.x;
    const int l0 = ((int)gridDim.y - 1 - (int)blockIdx.y) * 16;   // heavy first
    const int t0 = blockIdx.z * 4;
    const int tid = threadIdx.x;
    const int ls = tid >> 4, hc = tid & 15;
    const int l  = l0 + ls;
    const int h0 = hc * 8;
    const int bT = b * T_;

    const int wmaxl = l0 + ((tid >> 6) << 2) + 3;   // wave covers ls = 4w..4w+3
    if (wmaxl < Xi[bT + t0]) return;                // whole window masked (prefix)
    int tend = t0;
#pragma unroll
    for (int tt = t0; tt < t0 + 4; ++tt)
        if (wmaxl >= Xi[bT + tt]) tend = tt + 1;    // valid t's are a prefix

    float we[48], vv[48];
    const __bf16* wr = web + ((size_t)(b * L_ + l)) * H_ + h0;
#pragma unroll
    for (int j = 0; j < 6; ++j) {
        uint4 u = *(const uint4*)(wr + j * 128);
        we[j*8+0] = bf_lo(u.x); we[j*8+1] = bf_hi(u.x);
        we[j*8+2] = bf_lo(u.y); we[j*8+3] = bf_hi(u.y);
        we[j*8+4] = bf_lo(u.z); we[j*8+5] = bf_hi(u.z);
        we[j*8+6] = bf_lo(u.w); we[j*8+7] = bf_hi(u.w);
    }
    const float* vp = V + h0;
#pragma unroll
    for (int j = 0; j < 6; ++j) {
        float4 a = *(const float4*)(vp + j * 128);
        float4 c = *(const float4*)(vp + j * 128 + 4);
        vv[j*8+0] = a.x; vv[j*8+1] = a.y; vv[j*8+2] = a.z; vv[j*8+3] = a.w;
        vv[j*8+4] = c.x; vv[j*8+5] = c.y; vv[j*8+6] = c.z; vv[j*8+7] = c.w;
    }

#pragma unroll 2
    for (int t = t0; t < tend; ++t) {
        const float* wdp = wdf + ((size_t)(bT + t)) * H_ + h0;
        float a0 = 0.f, a1 = 0.f, a2 = 0.f, a3 = 0.f;
#pragma unroll
        for (int j = 0; j < 6; ++j) {
            float4 x = *(const float4*)(wdp + j * 128);
            float4 y = *(const float4*)(wdp + j * 128 + 4);
            a0 = fmaf(selu_core(we[j*8+0] + x.x), vv[j*8+0], a0);
            a1 = fmaf(selu_core(we[j*8+1] + x.y), vv[j*8+1], a1);
            a2 = fmaf(selu_core(we[j*8+2] + x.z), vv[j*8+2], a2);
            a3 = fmaf(selu_core(we[j*8+3] + x.w), vv[j*8+3], a3);
            a0 = fmaf(selu_core(we[j*8+4] + y.x), vv[j*8+4], a0);
            a1 = fmaf(selu_core(we[j*8+5] + y.y), vv[j*8+5], a1);
            a2 = fmaf(selu_core(we[j*8+6] + y.z), vv[j*8+6], a2);
            a3 = fmaf(selu_core(we[j*8+7] + y.w), vv[j*8+7], a3);
        }
        float dot = (a0 + a1) + (a2 + a3);
        dot += __shfl_xor(dot, 1);
        dot += __shfl_xor(dot, 2);
        dot += __shfl_xor(dot, 4);
        dot += __shfl_xor(dot, 8);
        if (hc == 0) {
            dot *= SELU_SCALE;
            float sc = dot > 0.0f ? SELU_SCALE * dot
                                  : SELU_SCALE * SELU_ALPHA * (__expf(dot) - 1.0f);
            scores[((size_t)(bT + t)) * L_ + l] = sc;
        }
    }
}

// ---------------- per-(b,t) masked logsumexp + gold + mean (atomic) -------------
__global__ __launch_bounds__(64) void loss_k(
        const float* __restrict__ scores, const int* __restrict__ Xi,
        const int* __restrict__ Yi, float* __restrict__ out) {
    const int bt = blockIdx.x;
    const int lane = threadIdx.x;
    const int X = Xi[bt];
    const int Y = Yi[bt];
    const float* row = scores + (size_t)bt * L_;

    float m = -INFINITY;
    for (int l = X + lane; l < L_; l += 64) m = fmaxf(m, row[l]);
#pragma unroll
    for (int off = 32; off > 0; off >>= 1) m = fmaxf(m, __shfl_xor(m, off));

    float s = 0.0f;
    for (int l = X + lane; l < L_; l += 64) s += __expf(row[l] - m);
#pragma unroll
    for (int off = 32; off > 0; off >>= 1) s += __shfl_xor(s, off);

    if (lane == 0)
        atomicAdd(out, (m + __logf(s) - row[Y]) * (1.0f / (B_ * T_)));
}

// ---------------- launch ----------------
extern "C" void kernel_launch(void* const* d_in, const int* in_sizes, int n_in,
                              void* d_out, int out_size, void* d_ws, size_t ws_size,
                              hipStream_t stream) {
    const float* hn  = (const float*)d_in[0];
    const float* dec = (const float*)d_in[1];
    const float* W1  = (const float*)d_in[2];
    const float* W2  = (const float*)d_in[3];
    const float* V   = (const float*)d_in[4];
    const int*   Xi  = (const int*)d_in[5];
    const int*   Yi  = (const int*)d_in[6];
    float* out = (float*)d_out;

    char* ws = (char*)d_ws;
    size_t off = 0;
    auto alloc = [&](size_t bytes) -> char* {
        char* p = ws + off;
        off += (bytes + 255) & ~(size_t)255;
        return p;
    };
    __bf16* web    = (__bf16*)alloc((size_t)B_ * L_ * H_ * 2);
    float*  wdf    = (float*)alloc((size_t)B_ * T_ * H_ * 4);
    float*  scores = (float*)alloc((size_t)B_ * T_ * L_ * 4);
    __bf16* allb   = (__bf16*)alloc((size_t)ALLELEM * 2);

    prep_k<<<ALLELEM / (256 * 8), 256, 0, stream>>>(hn, dec, W1, W2, Yi, allb, out);
    gemm_k<<<396, 256, 0, stream>>>(allb, web, wdf);
    scores_k<<<dim3(B_, L_ / 16, 4), 256, 0, stream>>>(web, wdf, V, Xi, scores);
    loss_k<<<B_ * T_, 64, 0, stream>>>(scores, Xi, Yi, out);
}

// Round 14
// 142.840 us; speedup vs baseline: 1.0452x; 1.0110x over previous
//
#include <hip/hip_runtime.h>
#include <hip/hip_bf16.h>
#include <math.h>

#define SELU_SCALE 1.0507009873554805f
#define SELU_ALPHA 1.6732632423543772f

static constexpr int B_ = 16, T_ = 16, L_ = 512, H_ = 768;
static constexpr int WSZ = 768 * 768;          // one weight matrix, elements
static constexpr int HNELEM = B_ * L_ * H_;    // 6291456
static constexpr int DJELEM = B_ * T_ * H_;    // 196608
// combined bf16 staging buffer layout: [hn | W1 | W2 | dj-gather]
static constexpr int ALLELEM = HNELEM + 2 * WSZ + DJELEM;   // 7667712 (/2048 = 3744)

typedef __bf16 bf16x8 __attribute__((ext_vector_type(8)));
typedef float  f32x4  __attribute__((ext_vector_type(4)));

__device__ __forceinline__ float bf_lo(unsigned u) { return __uint_as_float(u << 16); }
__device__ __forceinline__ float bf_hi(unsigned u) { return __uint_as_float(u & 0xFFFF0000u); }

__device__ __forceinline__ float selu_core(float x) {
    float e = fmaf(__expf(x), SELU_ALPHA, -SELU_ALPHA);
    return x > 0.0f ? x : e;
}

// LDS k-segment slot swizzle: slot = seg ^ ((row>>1)&3). Measured 0 conflicts
// for these write/read patterns. Note xsw(r+16) == xsw(r), so fragment offsets
// are affine in the 16-row fragment index.
__device__ __forceinline__ int xsw(int r) { return (r >> 1) & 3; }

__device__ __forceinline__ bf16x8 pack8(float4 a, float4 b) {
    bf16x8 o;
    o[0] = (__bf16)a.x; o[1] = (__bf16)a.y; o[2] = (__bf16)a.z; o[3] = (__bf16)a.w;
    o[4] = (__bf16)b.x; o[5] = (__bf16)b.y; o[6] = (__bf16)b.z; o[7] = (__bf16)b.w;
    return o;
}

// ---------------- prep: {hn, W1, W2, dec-gather} -> bf16 (one pass, ~7us) -------
// r3/r4-proven bit-identical (same RTN rounding as the old in-register staging).
// Enables gemm_k's global_load_lds DMA staging. Also zeroes the loss accumulator.
__global__ __launch_bounds__(256) void prep_k(
        const float* __restrict__ hn, const float* __restrict__ dec,
        const float* __restrict__ w1, const float* __restrict__ w2,
        const int* __restrict__ Yi,
        __bf16* __restrict__ allb, float* __restrict__ out) {
    if (blockIdx.x == 0 && threadIdx.x == 0) out[0] = 0.0f;
    int idx = (blockIdx.x * 256 + threadIdx.x) * 8;
    const float* src;
    if (idx < HNELEM) {
        src = hn + idx;
    } else if (idx < HNELEM + WSZ) {
        src = w1 + (idx - HNELEM);
    } else if (idx < HNELEM + 2 * WSZ) {
        src = w2 + (idx - HNELEM - WSZ);
    } else {
        int e = idx - (HNELEM + 2 * WSZ);      // < 196608
        int r = e / 768, c = e - r * 768;      // r = bt, 8 elems stay in-row
        src = dec + ((size_t)((r >> 4) * L_ + Yi[r])) * H_ + c;
    }
    float4 a = *(const float4*)src;
    float4 b = *(const float4*)(src + 4);
    *(bf16x8*)(allb + idx) = pack8(a, b);
}

// ---------------- fused NT GEMM: gload_lds + counted-vmcnt 3-buffer (r11 best) --
// FINAL CONFIG -- r13 post-mortem: depth-4/vmcnt(8) was within-noise-negative
// (144.4 vs 142.1); at 2 blk/CU the depth-3 wait rarely blocks (one tile of
// slack covers L2 latency), so depth is exhausted. Reverted to the measured-best
// r11 geometry: 128x128 tile, BK=32, 3 buffers x 16KB = 48KB LDS, 396 blocks,
// 4 waves of 64x64. Steady wait vmcnt(4): newest stage's 4 DMA ops stay in
// flight across the barrier (in-order retirement => oldest stage landed).
// Final tile peeled with vmcnt(0) (r9 tail-race fix: only 4 ops outstanding
// there). Race audit: STAGE(t+2) issues AFTER barrier(t); buf[(t+2)%3] was
// last read at iter t-1, sealed by that barrier. sched_barrier(0) pins
// COMPUTE's ds_reads below the sync. Pre-swizzled DMA source (xsw; LDS linear
// per m104/m173), measured-0-conflict fragment reads.
// Ledger: r8 DMA staging (win) > r10 counted-vmcnt d3 (win) > r12 64n tile
// (loss: staging bytes/output beats occupancy) > r13 d4 (neutral-negative).
__global__ __launch_bounds__(256, 2) void gemm_k(
        const __bf16* __restrict__ allb,
        __bf16* __restrict__ web, float* __restrict__ wdf) {
    __shared__ __bf16 sm[3][2][4096];   // [buf][A/B][128*32] = 48 KB

    int bx = blockIdx.x;
    const __bf16 *Ab, *Bb; int m0, n0; bool wd;
    if (bx < 384) {                      // WE: 64 m-tiles x 6 n-chunks
        wd = false; Ab = allb; Bb = allb + HNELEM;
        m0 = (bx & 63) * 128; n0 = (bx >> 6) * 128;
    } else {                             // WD: 2 m-tiles x 6 n-chunks
        wd = true; bx -= 384;
        Ab = allb + HNELEM + 2 * WSZ; Bb = allb + HNELEM + WSZ;
        m0 = (bx & 1) * 128;  n0 = (bx >> 1) * 128;
    }

    const int tid = threadIdx.x, wave = tid >> 6, lane = tid & 63;
    const int wm = (wave >> 1) * 64, wn = (wave & 1) * 64;
    const int lr = lane & 15, q = lane >> 4;
    const int l4 = lane >> 2, sl = lane & 3;

    // staging rows: instr0 -> rows wave*16 + l4 (0..63), instr1 -> +64.
    // lane's 16B lands at ldsBase + lane*16 (linear); pre-swizzled global seg.
    const int ar0 = wave * 16 + l4, ar1 = ar0 + 64;
    const __bf16* gA0 = Ab + (size_t)(m0 + ar0) * 768 + (sl ^ xsw(ar0)) * 8;
    const __bf16* gA1 = Ab + (size_t)(m0 + ar1) * 768 + (sl ^ xsw(ar1)) * 8;
    const __bf16* gB0 = Bb + (size_t)(n0 + ar0) * 768 + (sl ^ xsw(ar0)) * 8;
    const __bf16* gB1 = Bb + (size_t)(n0 + ar1) * 768 + (sl ^ xsw(ar1)) * 8;
    const int ld0 = wave * 512;          // element offset of this wave's 1KB slice
    const int ld1 = 2048 + wave * 512;

    // fragment base offsets (xsw(r+16)==xsw(r) -> affine in fragment index)
    const int aoff0 = (wm + lr) * 32 + (q ^ xsw(wm + lr)) * 8;
    const int boff0 = (wn + lr) * 32 + (q ^ xsw(wn + lr)) * 8;

    f32x4 acc[4][4] = {};

#define STAGE(b, kk)                                                                        \
    {                                                                                       \
        __builtin_amdgcn_global_load_lds((const __attribute__((address_space(1))) void*)(gA0 + (kk)), \
            (__attribute__((address_space(3))) void*)&sm[b][0][ld0], 16, 0, 0);             \
        __builtin_amdgcn_global_load_lds((const __attribute__((address_space(1))) void*)(gA1 + (kk)), \
            (__attribute__((address_space(3))) void*)&sm[b][0][ld1], 16, 0, 0);             \
        __builtin_amdgcn_global_load_lds((const __attribute__((address_space(1))) void*)(gB0 + (kk)), \
            (__attribute__((address_space(3))) void*)&sm[b][1][ld0], 16, 0, 0);             \
        __builtin_amdgcn_global_load_lds((const __attribute__((address_space(1))) void*)(gB1 + (kk)), \
            (__attribute__((address_space(3))) void*)&sm[b][1][ld1], 16, 0, 0);             \
    }

#define COMPUTE(b)                                                                          \
    {                                                                                       \
        bf16x8 af[4], bfr[4];                                                               \
        _Pragma("unroll")                                                                   \
        for (int i = 0; i < 4; ++i) af[i]  = *(const bf16x8*)&sm[b][0][aoff0 + i * 512];    \
        _Pragma("unroll")                                                                   \
        for (int j = 0; j < 4; ++j) bfr[j] = *(const bf16x8*)&sm[b][1][boff0 + j * 512];    \
        _Pragma("unroll")                                                                   \
        for (int i = 0; i < 4; ++i)                                                         \
            _Pragma("unroll")                                                               \
            for (int j = 0; j < 4; ++j)                                                     \
                acc[i][j] = __builtin_amdgcn_mfma_f32_16x16x32_bf16(af[i], bfr[j], acc[i][j], 0, 0, 0); \
    }

// one steady-state k-step: wait until the oldest in-flight stage landed
// (<=4 outstanding, in-order retirement), barrier, prefetch tile tt+2, compute
// tile tt. Valid for tt <= 22 (two stages in flight at the wait).
#define ITER(tt, bc, bs)                                                                    \
    {                                                                                       \
        asm volatile("s_waitcnt vmcnt(4)" ::: "memory");                                    \
        __builtin_amdgcn_s_barrier();                                                       \
        __builtin_amdgcn_sched_barrier(0);                                                  \
        if ((tt) + 2 < 24) STAGE(bs, ((tt) + 2) * 32)                                       \
        COMPUTE(bc)                                                                         \
    }

    // prologue: stage tiles 0 and 1 (no drain -- ITER's vmcnt(4) covers it)
    STAGE(0, 0)
    STAGE(1, 32)

#pragma unroll 1
    for (int g = 0; g < 7; ++g) {       // tiles 0..20
        const int t0g = g * 3;
        ITER(t0g + 0, 0, 2)
        ITER(t0g + 1, 1, 0)
        ITER(t0g + 2, 2, 1)
    }
    ITER(21, 0, 2)                      // stages tile 23 into buf 2
    ITER(22, 1, 0)                      // stages nothing (22 retired by this wait)
    // FINAL tile 23: only 4 ops outstanding here -- vmcnt(4) would NOT wait.
    // Drain fully, then one barrier so all waves' DMA is visible.
    asm volatile("s_waitcnt vmcnt(0)" ::: "memory");
    __builtin_amdgcn_s_barrier();
    __builtin_amdgcn_sched_barrier(0);
    COMPUTE(2)
#undef ITER
#undef STAGE
#undef COMPUTE

#pragma unroll
    for (int i = 0; i < 4; ++i)
#pragma unroll
        for (int j = 0; j < 4; ++j)
#pragma unroll
            for (int r = 0; r < 4; ++r) {
                int row = m0 + wm + i * 16 + q * 4 + r;
                int col = n0 + wn + j * 16 + lr;
                if (!wd) web[(size_t)row * 768 + col] = (__bf16)acc[i][j][r];
                else     wdf[(size_t)row * 768 + col] = acc[i][j][r];
            }
}

// ---------------- scores: LDS-free, register-cached, z-split 4 for occupancy ----
// Block = (b, 16 l rows, 4 t's). 256 thr = 16 ls x 16 hc. Thread owns the 48
// h-elements {hc*8 + j*128 + e}, keeps we (unpacked bf16) and V in registers,
// streams wd[t] (f32, L2-resident) per t. Grid 16x32x4 = 2048 blocks = 8/CU =
// 32 waves/CU (r11-verified win). Xindex monotone in t -> valid t's form a
// PREFIX per wave: tend computed once, loop branch-free, fully-masked waves
// exit BEFORE the 24 we/vv loads. unroll 2 interleaves two t-chains. lb(256,4)
// keeps we/vv hoisted (r2: no-hint sank them into the loop).
__global__ __launch_bounds__(256, 4) void scores_k(
        const __bf16* __restrict__ web, const float* __restrict__ wdf,
        const float* __restrict__ V, const int* __restrict__ Xi,
        float* __restrict__ scores) {
    const int b  = blockIdx.x;
    const int l0 = ((int)gridDim.y - 1 - (int)blockIdx.y) * 16;   // heavy first
    const int t0 = blockIdx.z * 4;
    const int tid = threadIdx.x;
    const int ls = tid >> 4, hc = tid & 15;
    const int l  = l0 + ls;
    const int h0 = hc * 8;
    const int bT = b * T_;

    const int wmaxl = l0 + ((tid >> 6) << 2) + 3;   // wave covers ls = 4w..4w+3
    if (wmaxl < Xi[bT + t0]) return;                // whole window masked (prefix)
    int tend = t0;
#pragma unroll
    for (int tt = t0; tt < t0 + 4; ++tt)
        if (wmaxl >= Xi[bT + tt]) tend = tt + 1;    // valid t's are a prefix

    float we[48], vv[48];
    const __bf16* wr = web + ((size_t)(b * L_ + l)) * H_ + h0;
#pragma unroll
    for (int j = 0; j < 6; ++j) {
        uint4 u = *(const uint4*)(wr + j * 128);
        we[j*8+0] = bf_lo(u.x); we[j*8+1] = bf_hi(u.x);
        we[j*8+2] = bf_lo(u.y); we[j*8+3] = bf_hi(u.y);
        we[j*8+4] = bf_lo(u.z); we[j*8+5] = bf_hi(u.z);
        we[j*8+6] = bf_lo(u.w); we[j*8+7] = bf_hi(u.w);
    }
    const float* vp = V + h0;
#pragma unroll
    for (int j = 0; j < 6; ++j) {
        float4 a = *(const float4*)(vp + j * 128);
        float4 c = *(const float4*)(vp + j * 128 + 4);
        vv[j*8+0] = a.x; vv[j*8+1] = a.y; vv[j*8+2] = a.z; vv[j*8+3] = a.w;
        vv[j*8+4] = c.x; vv[j*8+5] = c.y; vv[j*8+6] = c.z; vv[j*8+7] = c.w;
    }

#pragma unroll 2
    for (int t = t0; t < tend; ++t) {
        const float* wdp = wdf + ((size_t)(bT + t)) * H_ + h0;
        float a0 = 0.f, a1 = 0.f, a2 = 0.f, a3 = 0.f;
#pragma unroll
        for (int j = 0; j < 6; ++j) {
            float4 x = *(const float4*)(wdp + j * 128);
            float4 y = *(const float4*)(wdp + j * 128 + 4);
            a0 = fmaf(selu_core(we[j*8+0] + x.x), vv[j*8+0], a0);
            a1 = fmaf(selu_core(we[j*8+1] + x.y), vv[j*8+1], a1);
            a2 = fmaf(selu_core(we[j*8+2] + x.z), vv[j*8+2], a2);
            a3 = fmaf(selu_core(we[j*8+3] + x.w), vv[j*8+3], a3);
            a0 = fmaf(selu_core(we[j*8+4] + y.x), vv[j*8+4], a0);
            a1 = fmaf(selu_core(we[j*8+5] + y.y), vv[j*8+5], a1);
            a2 = fmaf(selu_core(we[j*8+6] + y.z), vv[j*8+6], a2);
            a3 = fmaf(selu_core(we[j*8+7] + y.w), vv[j*8+7], a3);
        }
        float dot = (a0 + a1) + (a2 + a3);
        dot += __shfl_xor(dot, 1);
        dot += __shfl_xor(dot, 2);
        dot += __shfl_xor(dot, 4);
        dot += __shfl_xor(dot, 8);
        if (hc == 0) {
            dot *= SELU_SCALE;
            float sc = dot > 0.0f ? SELU_SCALE * dot
                                  : SELU_SCALE * SELU_ALPHA * (__expf(dot) - 1.0f);
            scores[((size_t)(bT + t)) * L_ + l] = sc;
        }
    }
}

// ---------------- per-(b,t) masked logsumexp + gold + mean (atomic) -------------
__global__ __launch_bounds__(64) void loss_k(
        const float* __restrict__ scores, const int* __restrict__ Xi,
        const int* __restrict__ Yi, float* __restrict__ out) {
    const int bt = blockIdx.x;
    const int lane = threadIdx.x;
    const int X = Xi[bt];
    const int Y = Yi[bt];
    const float* row = scores + (size_t)bt * L_;

    float m = -INFINITY;
    for (int l = X + lane; l < L_; l += 64) m = fmaxf(m, row[l]);
#pragma unroll
    for (int off = 32; off > 0; off >>= 1) m = fmaxf(m, __shfl_xor(m, off));

    float s = 0.0f;
    for (int l = X + lane; l < L_; l += 64) s += __expf(row[l] - m);
#pragma unroll
    for (int off = 32; off > 0; off >>= 1) s += __shfl_xor(s, off);

    if (lane == 0)
        atomicAdd(out, (m + __logf(s) - row[Y]) * (1.0f / (B_ * T_)));
}

// ---------------- launch ----------------
extern "C" void kernel_launch(void* const* d_in, const int* in_sizes, int n_in,
                              void* d_out, int out_size, void* d_ws, size_t ws_size,
                              hipStream_t stream) {
    const float* hn  = (const float*)d_in[0];
    const float* dec = (const float*)d_in[1];
    const float* W1  = (const float*)d_in[2];
    const float* W2  = (const float*)d_in[3];
    const float* V   = (const float*)d_in[4];
    const int*   Xi  = (const int*)d_in[5];
    const int*   Yi  = (const int*)d_in[6];
    float* out = (float*)d_out;

    char* ws = (char*)d_ws;
    size_t off = 0;
    auto alloc = [&](size_t bytes) -> char* {
        char* p = ws + off;
        off += (bytes + 255) & ~(size_t)255;
        return p;
    };
    __bf16* web    = (__bf16*)alloc((size_t)B_ * L_ * H_ * 2);
    float*  wdf    = (float*)alloc((size_t)B_ * T_ * H_ * 4);
    float*  scores = (float*)alloc((size_t)B_ * T_ * L_ * 4);
    __bf16* allb   = (__bf16*)alloc((size_t)ALLELEM * 2);

    prep_k<<<ALLELEM / (256 * 8), 256, 0, stream>>>(hn, dec, W1, W2, Yi, allb, out);
    gemm_k<<<396, 256, 0, stream>>>(allb, web, wdf);
    scores_k<<<dim3(B_, L_ / 16, 4), 256, 0, stream>>>(web, wdf, V, Xi, scores);
    loss_k<<<B_ * T_, 64, 0, stream>>>(scores, Xi, Yi, out);
}